// Round 8
// baseline (386.793 us; speedup 1.0000x reference)
//
#include <hip/hip_runtime.h>
#include <hip/hip_bf16.h>
#include <hip/hip_cooperative_groups.h>
#include <math.h>

#define DIMC 128

typedef __attribute__((ext_vector_type(8))) short short8;
typedef __attribute__((ext_vector_type(4))) float floatx4;

namespace cg = cooperative_groups;

// bf16 helpers
static __device__ __forceinline__ unsigned pk2(float lo, float hi) {
    __hip_bfloat162 h = __float22bfloat162_rn(make_float2(lo, hi));  // v_cvt_pk_bf16_f32
    return *(unsigned*)&h;
}
static __device__ __forceinline__ unsigned short f2bf(float x) {
    union { float f; unsigned int u; } v; v.f = x;
    unsigned int r = v.u + 0x7FFFu + ((v.u >> 16) & 1u);
    return (unsigned short)(r >> 16);
}
static __device__ __forceinline__ float2 bf2f2(unsigned int u) {
    union { unsigned int i; float f; } a, b;
    a.i = u << 16; b.i = u & 0xFFFF0000u;
    return make_float2(a.f, b.f);
}
static __device__ __forceinline__ int aload(const int* p) {
    return __hip_atomic_load(p, __ATOMIC_RELAXED, __HIP_MEMORY_SCOPE_AGENT);
}

// ---------------- fused prep: W fragments (6 mats) + TypeEmb staging + deg zero -------------
// F[(t*4+s)*64 + lane] = 8 bf16: W[s*32 + (lane>>4)*8 + j][t*16 + (lane&15)]
struct PrepArgs {
    const float* W[6];
    unsigned short* F[6];
    const float* relemb; const float* selfrel;
    float* TypeEmb;
    int* deg;
    int R; int N;
};

__global__ __launch_bounds__(64) void prep_all(PrepArgs a)
{
    int b = blockIdx.x;
    int lane = threadIdx.x;
    if (b < 192) {                       // fragment build
        int mat = b >> 5, ts = b & 31;
        int s = ts & 3, t = ts >> 2;
        int q = lane >> 4, c = lane & 15;
        const float* W = a.W[mat];
        unsigned short o[8];
        #pragma unroll
        for (int j = 0; j < 8; ++j)
            o[j] = f2bf(W[(long)(s * 32 + q * 8 + j) * DIMC + t * 16 + c]);
        uint4 u;
        u.x = (unsigned)o[0] | ((unsigned)o[1] << 16);
        u.y = (unsigned)o[2] | ((unsigned)o[3] << 16);
        u.z = (unsigned)o[4] | ((unsigned)o[5] << 16);
        u.w = (unsigned)o[6] | ((unsigned)o[7] << 16);
        ((uint4*)a.F[mat])[ts * 64 + lane] = u;
    } else if (b < 192 + a.R + 1) {      // TypeEmb row copy (f32)
        int r = b - 192;
        const float* src = (r < a.R) ? (a.relemb + (long)r * DIMC) : a.selfrel;
        float2 v = ((const float2*)src)[lane];
        ((float2*)(a.TypeEmb + (long)r * DIMC))[lane] = v;
    } else {                              // deg zero
        int i = (b - (192 + a.R + 1)) * 64 + lane;
        if (i < a.N) a.deg[i] = 0;
    }
}

// ---------------- MFMA GEMM, 5 slices ----------------
struct GemmM5 {
    const float*          Af[5];
    const unsigned short* Ab[5];
    const unsigned short* F[5];
    const float*          bias[5];
    float*                outf[5];
    unsigned short*       outb[5];
    int                   ostride[5];
    int                   ooff[5];
    int                   M[5];
};

__global__ __launch_bounds__(256) void gemm_mfma(GemmM5 g)
{
    const int which = blockIdx.y;
    const int M = g.M[which];
    if (blockIdx.x * 64 >= M) return;

    const float*          __restrict__ Af   = g.Af[which];
    const unsigned short* __restrict__ Ab   = g.Ab[which];
    const unsigned short* __restrict__ F    = g.F[which];
    const float*          __restrict__ bias = g.bias[which];
    float*          __restrict__ outf = g.outf[which];
    unsigned short* __restrict__ outb = g.outb[which];
    const int ostride = g.ostride[which];
    const int ooff    = g.ooff[which];

    const int wave = threadIdx.x >> 6;
    const int lane = threadIdx.x & 63;
    const int q = lane >> 4, c = lane & 15;
    const int rowbase = blockIdx.x * 64 + wave * 16;

    short8 wf[8][4];
    const uint4* Fp = (const uint4*)F;
    #pragma unroll
    for (int t = 0; t < 8; ++t)
        #pragma unroll
        for (int s = 0; s < 4; ++s) {
            uint4 u = Fp[(t * 4 + s) * 64 + lane];
            wf[t][s] = *(short8*)&u;
        }

    floatx4 acc[8];
    #pragma unroll
    for (int t = 0; t < 8; ++t) {
        float b = bias ? bias[t * 16 + c] : 0.0f;
        acc[t] = (floatx4){b, b, b, b};
    }

    int rowA = rowbase + c; if (rowA > M - 1) rowA = M - 1;   // clamp (tail tiles)
    short8 af[4];
    if (Af) {
        const float* Ar = Af + (long)rowA * DIMC + q * 8;
        #pragma unroll
        for (int s = 0; s < 4; ++s) {
            float4 x0 = *(const float4*)(Ar + s * 32);
            float4 x1 = *(const float4*)(Ar + s * 32 + 4);
            uint4 u;
            u.x = pk2(x0.x, x0.y);
            u.y = pk2(x0.z, x0.w);
            u.z = pk2(x1.x, x1.y);
            u.w = pk2(x1.z, x1.w);
            af[s] = *(short8*)&u;
        }
    } else {
        const unsigned short* Ar = Ab + (long)rowA * DIMC + q * 8;
        #pragma unroll
        for (int s = 0; s < 4; ++s) {
            uint4 u = *(const uint4*)(Ar + s * 32);
            af[s] = *(short8*)&u;
        }
    }

    #pragma unroll
    for (int t = 0; t < 8; ++t)
        #pragma unroll
        for (int s = 0; s < 4; ++s)
            acc[t] = __builtin_amdgcn_mfma_f32_16x16x32_bf16(af[s], wf[t][s], acc[t], 0, 0, 0);

    // epilogue: C/D layout col = t*16 + c, row = rowbase + q*4 + r
    if (outf) {
        #pragma unroll
        for (int t = 0; t < 8; ++t)
            #pragma unroll
            for (int r = 0; r < 4; ++r) {
                int row = rowbase + q * 4 + r;
                if (row < M)
                    outf[(long)row * DIMC + t * 16 + c] = acc[t][r];
            }
    } else {
        #pragma unroll
        for (int t = 0; t < 8; ++t)
            #pragma unroll
            for (int r = 0; r < 4; ++r) {
                float other = __shfl_xor(acc[t][r], 1);
                int row = rowbase + q * 4 + r;
                if ((lane & 1) == 0 && row < M) {
                    unsigned word = pk2(acc[t][r], other);
                    ((unsigned*)outb)[((long)row * 64 + t * 8 + (c >> 1))
                                      * (long)ostride + ooff] = word;
                }
            }
    }
}

// ---------------- cooperative CSR build: hist + scan + scatter in one dispatch -------------
struct CsrArgs {
    const int* esrc; const int* edst; const int* etype;
    int* deg; int* offs; int* cursor;
    int* partial; int* baseArr;
    int2* sedge;
    int N; int E; int nblk;
};

__global__ __launch_bounds__(1024) void csr_coop(CsrArgs a)
{
    cg::grid_group grid = cg::this_grid();
    const int b = blockIdx.x, t = threadIdx.x;
    const int lane = t & 63, wid = t >> 6;
    const int gsz = gridDim.x * 1024;

    // phase 1: histogram (deg pre-zeroed by prep_all)
    for (int e = b * 1024 + t; e < a.E; e += gsz)
        atomicAdd(&a.deg[a.edst[e]], 1);
    __threadfence();
    grid.sync();

    // phase 2a: block-local inclusive scan (1 element/thread; N <= gsz)
    __shared__ int wsum[16], wbase[16];
    int i = b * 1024 + t;
    int d_i = (i < a.N) ? aload(&a.deg[i]) : 0;
    int v = d_i;
    #pragma unroll
    for (int d = 1; d < 64; d <<= 1) {
        int u = __shfl_up(v, d);
        if (lane >= d) v += u;
    }
    if (lane == 63) wsum[wid] = v;
    __syncthreads();
    if (wid == 0 && lane < 16) {
        int s = wsum[lane];
        #pragma unroll
        for (int d = 1; d < 16; d <<= 1) {
            int u = __shfl_up(s, d);
            if (lane >= d) s += u;
        }
        wbase[lane] = s - wsum[lane];
        if (lane == 15) a.partial[b] = s;
    }
    __syncthreads();
    int incl = v + wbase[wid];
    int excl = incl - d_i;
    __threadfence();
    grid.sync();

    // phase 2b: block 0 scans the per-block partials
    if (b == 0) {
        __shared__ int sb[128];
        int val = (t < a.nblk) ? aload(&a.partial[t]) : 0;
        if (t < 128) sb[t] = val;
        __syncthreads();
        for (int d = 1; d < 128; d <<= 1) {
            int u = (t >= d && t < 128) ? sb[t - d] : 0;
            __syncthreads();
            if (t < 128) sb[t] += u;
            __syncthreads();
        }
        if (t < a.nblk) a.baseArr[t] = sb[t] - val;   // exclusive base
    }
    __threadfence();
    grid.sync();

    // phase 2c: write offsets + cursor
    int bb = aload(&a.baseArr[b]);
    if (i < a.N) {
        a.offs[i]   = bb + excl;
        a.cursor[i] = bb + excl;
    }
    __threadfence();
    grid.sync();

    // phase 3: scatter
    for (int e = b * 1024 + t; e < a.E; e += gsz) {
        int d = a.edst[e];
        int p = atomicAdd(&a.cursor[d], 1);
        a.sedge[p] = make_int2(a.esrc[e], a.etype[e]);
    }
}

// ---------------- per-node flash-style dual softmax + V aggregation ----------------
__global__ __launch_bounds__(256) void node_kernel(
    const float* __restrict__ Qn,
    const uint2* __restrict__ KV,     // [n*64 + lane] = {K pair, V pair}
    const uint2* __restrict__ QKre,   // [t*64 + lane] = {Qre pair, Kre pair}
    const int* __restrict__ offs, const int* __restrict__ deg,
    const int2* __restrict__ sedge,
    float* __restrict__ out_sta, unsigned* __restrict__ feat_dyn,
    int N, int R)
{
    int n = (blockIdx.x * blockDim.x + threadIdx.x) >> 6;
    int lane = threadIdx.x & 63;
    if (n >= N) return;

    const float cs = 0.08838834764831845f * 1.4426950408889634f;  // (1/sqrt(128))*log2(e)
    int base = offs[n];
    int dcnt = deg[n];

    float2 qn = ((const float2*)(Qn + (long)n * DIMC))[lane];

    uint2 kvs = KV[(unsigned)n * 64u + lane];
    uint2 qks = QKre[(unsigned)R * 64u + lane];
    float2 ks = bf2f2(kvs.x), vs = bf2f2(kvs.y);
    float2 qr = bf2f2(qks.x), kr = bf2f2(qks.y);
    float p = (qn.x + qr.x) * (ks.x + kr.x) + (qn.y + qr.y) * (ks.y + kr.y);
    #pragma unroll
    for (int m = 32; m >= 1; m >>= 1) p += __shfl_xor(p, m);
    float a_self = p * cs;

    float m_dyn = a_self, s_dyn = 1.0f;
    float m_sta = -a_self, s_sta = 1.0f;
    float2 accd = vs;
    float2 accs = vs;

    int i = 0;
    for (; i + 4 <= dcnt; i += 4) {
        int2 e0 = sedge[base + i],     e1 = sedge[base + i + 1];
        int2 e2 = sedge[base + i + 2], e3 = sedge[base + i + 3];

        uint2 kv0 = KV[(unsigned)e0.x * 64u + lane];
        uint2 kv1 = KV[(unsigned)e1.x * 64u + lane];
        uint2 kv2 = KV[(unsigned)e2.x * 64u + lane];
        uint2 kv3 = KV[(unsigned)e3.x * 64u + lane];
        uint2 t0 = QKre[(unsigned)e0.y * 64u + lane];
        uint2 t1 = QKre[(unsigned)e1.y * 64u + lane];
        uint2 t2 = QKre[(unsigned)e2.y * 64u + lane];
        uint2 t3 = QKre[(unsigned)e3.y * 64u + lane];

        float2 kn0 = bf2f2(kv0.x), v0 = bf2f2(kv0.y);
        float2 kn1 = bf2f2(kv1.x), v1 = bf2f2(kv1.y);
        float2 kn2 = bf2f2(kv2.x), v2 = bf2f2(kv2.y);
        float2 kn3 = bf2f2(kv3.x), v3 = bf2f2(kv3.y);
        float2 q0 = bf2f2(t0.x), k0 = bf2f2(t0.y);
        float2 q1 = bf2f2(t1.x), k1 = bf2f2(t1.y);
        float2 q2 = bf2f2(t2.x), k2 = bf2f2(t2.y);
        float2 q3 = bf2f2(t3.x), k3 = bf2f2(t3.y);

        float p0 = (qn.x + q0.x) * (kn0.x + k0.x) + (qn.y + q0.y) * (kn0.y + k0.y);
        float p1 = (qn.x + q1.x) * (kn1.x + k1.x) + (qn.y + q1.y) * (kn1.y + k1.y);
        float p2 = (qn.x + q2.x) * (kn2.x + k2.x) + (qn.y + q2.y) * (kn2.y + k2.y);
        float p3 = (qn.x + q3.x) * (kn3.x + k3.x) + (qn.y + q3.y) * (kn3.y + k3.y);
        #pragma unroll
        for (int m = 32; m >= 1; m >>= 1) {
            p0 += __shfl_xor(p0, m);
            p1 += __shfl_xor(p1, m);
            p2 += __shfl_xor(p2, m);
            p3 += __shfl_xor(p3, m);
        }
        float a0 = p0 * cs, a1 = p1 * cs, a2 = p2 * cs, a3 = p3 * cs;

        float mx = fmaxf(fmaxf(a0, a1), fmaxf(a2, a3));
        float mn = fmaxf(m_dyn, mx);
        float f  = exp2f(m_dyn - mn);
        float w0 = exp2f(a0 - mn), w1 = exp2f(a1 - mn);
        float w2 = exp2f(a2 - mn), w3 = exp2f(a3 - mn);
        s_dyn = fmaf(s_dyn, f, (w0 + w1) + (w2 + w3));
        accd.x = fmaf(accd.x, f, fmaf(w0, v0.x, fmaf(w1, v1.x, fmaf(w2, v2.x, w3 * v3.x))));
        accd.y = fmaf(accd.y, f, fmaf(w0, v0.y, fmaf(w1, v1.y, fmaf(w2, v2.y, w3 * v3.y))));
        m_dyn = mn;

        float nmx = -fminf(fminf(a0, a1), fminf(a2, a3));
        float ms = fmaxf(m_sta, nmx);
        float fs = exp2f(m_sta - ms);
        float u0 = exp2f(-a0 - ms), u1 = exp2f(-a1 - ms);
        float u2 = exp2f(-a2 - ms), u3 = exp2f(-a3 - ms);
        s_sta = fmaf(s_sta, fs, (u0 + u1) + (u2 + u3));
        accs.x = fmaf(accs.x, fs, fmaf(u0, v0.x, fmaf(u1, v1.x, fmaf(u2, v2.x, u3 * v3.x))));
        accs.y = fmaf(accs.y, fs, fmaf(u0, v0.y, fmaf(u1, v1.y, fmaf(u2, v2.y, u3 * v3.y))));
        m_sta = ms;
    }

    for (; i < dcnt; ++i) {
        int2 e = sedge[base + i];
        uint2 kv = KV[(unsigned)e.x * 64u + lane];
        uint2 tt = QKre[(unsigned)e.y * 64u + lane];
        float2 kn = bf2f2(kv.x), v = bf2f2(kv.y);
        float2 q2 = bf2f2(tt.x), k2 = bf2f2(tt.y);
        float pp = (qn.x + q2.x) * (kn.x + k2.x) + (qn.y + q2.y) * (kn.y + k2.y);
        #pragma unroll
        for (int m = 32; m >= 1; m >>= 1) pp += __shfl_xor(pp, m);
        float a = pp * cs;

        float mn = fmaxf(m_dyn, a);
        float fd = exp2f(m_dyn - mn);
        float wd = exp2f(a - mn);
        s_dyn = fmaf(s_dyn, fd, wd);
        accd.x = fmaf(accd.x, fd, wd * v.x);
        accd.y = fmaf(accd.y, fd, wd * v.y);
        m_dyn = mn;

        float ms = fmaxf(m_sta, -a);
        float fs = exp2f(m_sta - ms);
        float ws_ = exp2f(-a - ms);
        s_sta = fmaf(s_sta, fs, ws_);
        accs.x = fmaf(accs.x, fs, ws_ * v.x);
        accs.y = fmaf(accs.y, fs, ws_ * v.y);
        m_sta = ms;
    }

    float denom = (float)(dcnt + 1);
    float id_ = 1.0f / (s_dyn * denom);
    float is_ = 1.0f / (s_sta * denom);
    ((float2*)(out_sta + (long)n * DIMC))[lane] = make_float2(accs.x * is_, accs.y * is_);
    feat_dyn[(unsigned)n * 64u + lane] = pk2(accd.x * id_, accd.y * id_);
}

// ---------------- launch ----------------
extern "C" void kernel_launch(void* const* d_in, const int* in_sizes, int n_in,
                              void* d_out, int out_size, void* d_ws, size_t ws_size,
                              hipStream_t stream)
{
    const float* curr    = (const float*)d_in[0];
    const float* last    = (const float*)d_in[1];
    const float* relemb  = (const float*)d_in[2];
    const float* selfrel = (const float*)d_in[3];
    const float* Wq      = (const float*)d_in[4];
    const float* bq      = (const float*)d_in[5];
    const float* Wk      = (const float*)d_in[6];
    const float* bk      = (const float*)d_in[7];
    const float* Wv      = (const float*)d_in[8];
    const float* bv      = (const float*)d_in[9];
    const float* dynw    = (const float*)d_in[10];
    const int*   eidx    = (const int*)d_in[11];
    const int*   etype   = (const int*)d_in[12];
    float* out = (float*)d_out;

    const int N = in_sizes[0] / DIMC;   // 40000
    const int E = in_sizes[12];         // 400000
    const int R = in_sizes[2] / DIMC;   // 502
    const int* esrc = eidx;
    const int* edst = eidx + E;

    char* wp = (char*)d_ws;
    auto alloc = [&](size_t bytes) { char* r = wp; wp += (bytes + 15) & ~(size_t)15; return r; };
    size_t nd = (size_t)N * DIMC;
    float*          Qn    = (float*)alloc(nd * 4);
    uint2*          KV    = (uint2*)alloc((size_t)N * 64 * 8);
    unsigned short* Fdb   = (unsigned short*)alloc(nd * 2);
    uint2*          QKre  = (uint2*)alloc((size_t)(R + 1) * 64 * 8);
    float*          TypeEmb = (float*)alloc((size_t)(R + 2) * DIMC * 4);
    unsigned short* FW[6];
    for (int m = 0; m < 6; ++m) FW[m] = (unsigned short*)alloc(2048 * 8 * 2);
    int*            deg   = (int*)alloc((size_t)N * 4);
    int*            offs  = (int*)alloc((size_t)N * 4);
    int*            cursor= (int*)alloc((size_t)N * 4);
    int2*           sedge = (int2*)alloc((size_t)E * 8);
    int*            partial = (int*)alloc(128 * 4);
    int*            baseArr = (int*)alloc(128 * 4);

    const int gblk = N / 64;   // 625

    // 1. fused prep
    PrepArgs pa;
    pa.W[0] = Wq;   pa.W[1] = Wk;   pa.W[2] = Wv;
    pa.W[3] = dynw; pa.W[4] = Wq + (size_t)DIMC * DIMC; pa.W[5] = Wk + (size_t)DIMC * DIMC;
    for (int m = 0; m < 6; ++m) pa.F[m] = FW[m];
    pa.relemb = relemb; pa.selfrel = selfrel; pa.TypeEmb = TypeEmb;
    pa.deg = deg; pa.R = R; pa.N = N;
    int pgrid = 192 + (R + 1) + (N + 63) / 64;
    hipLaunchKernelGGL(prep_all, dim3(pgrid), dim3(64), 0, stream, pa);

    // 2. cooperative CSR build (independent of prep except deg-zero ordering on stream)
    CsrArgs ca;
    ca.esrc = esrc; ca.edst = edst; ca.etype = etype;
    ca.deg = deg; ca.offs = offs; ca.cursor = cursor;
    ca.partial = partial; ca.baseArr = baseArr; ca.sedge = sedge;
    ca.N = N; ca.E = E; ca.nblk = 80;
    void* cargs[] = { &ca };
    hipLaunchCooperativeKernel((const void*)csr_coop, dim3(80), dim3(1024), cargs, 0, stream);

    // 3. all five projections in one MFMA dispatch
    GemmM5 g5;
    for (int s = 0; s < 5; ++s) { g5.Ab[s] = nullptr; g5.outf[s] = nullptr; g5.outb[s] = nullptr; }
    g5.Af[0] = curr;    g5.F[0] = FW[0]; g5.bias[0] = nullptr; g5.outf[0] = Qn;
    g5.ostride[0] = 1;  g5.ooff[0] = 0;  g5.M[0] = N;
    g5.Af[1] = last;    g5.F[1] = FW[1]; g5.bias[1] = nullptr; g5.outb[1] = (unsigned short*)KV;
    g5.ostride[1] = 2;  g5.ooff[1] = 0;  g5.M[1] = N;
    g5.Af[2] = last;    g5.F[2] = FW[2]; g5.bias[2] = bv;      g5.outb[2] = (unsigned short*)KV;
    g5.ostride[2] = 2;  g5.ooff[2] = 1;  g5.M[2] = N;
    g5.Af[3] = TypeEmb; g5.F[3] = FW[4]; g5.bias[3] = bq;      g5.outb[3] = (unsigned short*)QKre;
    g5.ostride[3] = 2;  g5.ooff[3] = 0;  g5.M[3] = R + 1;
    g5.Af[4] = TypeEmb; g5.F[4] = FW[5]; g5.bias[4] = bk;      g5.outb[4] = (unsigned short*)QKre;
    g5.ostride[4] = 2;  g5.ooff[4] = 1;  g5.M[4] = R + 1;
    hipLaunchKernelGGL(gemm_mfma, dim3(gblk, 5), dim3(256), 0, stream, g5);

    // 4. node aggregation
    hipLaunchKernelGGL(node_kernel, dim3((N + 3) / 4), dim3(256), 0, stream,
                       Qn, KV, QKre, offs, deg, sedge, out, (unsigned*)Fdb, N, R);

    // 5. final GEMM: feat_dyn @ dyn_weight
    GemmM5 gf;
    for (int s = 0; s < 5; ++s) { gf.Af[s] = nullptr; gf.Ab[s] = nullptr; gf.outf[s] = nullptr; gf.outb[s] = nullptr; gf.M[s] = 0; }
    gf.Ab[0] = Fdb; gf.F[0] = FW[3]; gf.bias[0] = nullptr; gf.outf[0] = out + nd;
    gf.ostride[0] = 1; gf.ooff[0] = 0; gf.M[0] = N;
    hipLaunchKernelGGL(gemm_mfma, dim3(gblk, 1), dim3(256), 0, stream, gf);
}

// Round 9
// 242.076 us; speedup vs baseline: 1.5978x; 1.5978x over previous
//
#include <hip/hip_runtime.h>
#include <hip/hip_bf16.h>
#include <math.h>

#define DIMC 128

typedef __attribute__((ext_vector_type(8))) short short8;
typedef __attribute__((ext_vector_type(4))) float floatx4;

// bf16 helpers
static __device__ __forceinline__ unsigned pk2(float lo, float hi) {
    __hip_bfloat162 h = __float22bfloat162_rn(make_float2(lo, hi));  // v_cvt_pk_bf16_f32
    return *(unsigned*)&h;
}
static __device__ __forceinline__ unsigned short f2bf(float x) {
    union { float f; unsigned int u; } v; v.f = x;
    unsigned int r = v.u + 0x7FFFu + ((v.u >> 16) & 1u);
    return (unsigned short)(r >> 16);
}
static __device__ __forceinline__ float2 bf2f2(unsigned int u) {
    union { unsigned int i; float f; } a, b;
    a.i = u << 16; b.i = u & 0xFFFF0000u;
    return make_float2(a.f, b.f);
}

// ---------------- fused prep: W fragments (6 mats) + TypeEmb staging + deg zero -------------
// F[(t*4+s)*64 + lane] = 8 bf16: W[s*32 + (lane>>4)*8 + j][t*16 + (lane&15)]
struct PrepArgs {
    const float* W[6];
    unsigned short* F[6];
    const float* relemb; const float* selfrel;
    float* TypeEmb;
    int* deg;
    int R; int N;
};

__global__ __launch_bounds__(64) void prep_all(PrepArgs a)
{
    int b = blockIdx.x;
    int lane = threadIdx.x;
    if (b < 192) {                       // fragment build
        int mat = b >> 5, ts = b & 31;
        int s = ts & 3, t = ts >> 2;
        int q = lane >> 4, c = lane & 15;
        const float* W = a.W[mat];
        unsigned short o[8];
        #pragma unroll
        for (int j = 0; j < 8; ++j)
            o[j] = f2bf(W[(long)(s * 32 + q * 8 + j) * DIMC + t * 16 + c]);
        uint4 u;
        u.x = (unsigned)o[0] | ((unsigned)o[1] << 16);
        u.y = (unsigned)o[2] | ((unsigned)o[3] << 16);
        u.z = (unsigned)o[4] | ((unsigned)o[5] << 16);
        u.w = (unsigned)o[6] | ((unsigned)o[7] << 16);
        ((uint4*)a.F[mat])[ts * 64 + lane] = u;
    } else if (b < 192 + a.R + 1) {      // TypeEmb row copy (f32)
        int r = b - 192;
        const float* src = (r < a.R) ? (a.relemb + (long)r * DIMC) : a.selfrel;
        float2 v = ((const float2*)src)[lane];
        ((float2*)(a.TypeEmb + (long)r * DIMC))[lane] = v;
    } else {                              // deg zero
        int i = (b - (192 + a.R + 1)) * 64 + lane;
        if (i < a.N) a.deg[i] = 0;
    }
}

// ---------------- MFMA GEMM, 5 slices ----------------
struct GemmM5 {
    const float*          Af[5];
    const unsigned short* Ab[5];
    const unsigned short* F[5];
    const float*          bias[5];
    float*                outf[5];
    unsigned short*       outb[5];
    int                   ostride[5];
    int                   ooff[5];
    int                   M[5];
};

__global__ __launch_bounds__(256) void gemm_mfma(GemmM5 g)
{
    const int which = blockIdx.y;
    const int M = g.M[which];
    if (blockIdx.x * 64 >= M) return;

    const float*          __restrict__ Af   = g.Af[which];
    const unsigned short* __restrict__ Ab   = g.Ab[which];
    const unsigned short* __restrict__ F    = g.F[which];
    const float*          __restrict__ bias = g.bias[which];
    float*          __restrict__ outf = g.outf[which];
    unsigned short* __restrict__ outb = g.outb[which];
    const int ostride = g.ostride[which];
    const int ooff    = g.ooff[which];

    const int wave = threadIdx.x >> 6;
    const int lane = threadIdx.x & 63;
    const int q = lane >> 4, c = lane & 15;
    const int rowbase = blockIdx.x * 64 + wave * 16;

    short8 wf[8][4];
    const uint4* Fp = (const uint4*)F;
    #pragma unroll
    for (int t = 0; t < 8; ++t)
        #pragma unroll
        for (int s = 0; s < 4; ++s) {
            uint4 u = Fp[(t * 4 + s) * 64 + lane];
            wf[t][s] = *(short8*)&u;
        }

    floatx4 acc[8];
    #pragma unroll
    for (int t = 0; t < 8; ++t) {
        float b = bias ? bias[t * 16 + c] : 0.0f;
        acc[t] = (floatx4){b, b, b, b};
    }

    int rowA = rowbase + c; if (rowA > M - 1) rowA = M - 1;   // clamp (tail tiles)
    short8 af[4];
    if (Af) {
        const float* Ar = Af + (long)rowA * DIMC + q * 8;
        #pragma unroll
        for (int s = 0; s < 4; ++s) {
            float4 x0 = *(const float4*)(Ar + s * 32);
            float4 x1 = *(const float4*)(Ar + s * 32 + 4);
            uint4 u;
            u.x = pk2(x0.x, x0.y);
            u.y = pk2(x0.z, x0.w);
            u.z = pk2(x1.x, x1.y);
            u.w = pk2(x1.z, x1.w);
            af[s] = *(short8*)&u;
        }
    } else {
        const unsigned short* Ar = Ab + (long)rowA * DIMC + q * 8;
        #pragma unroll
        for (int s = 0; s < 4; ++s) {
            uint4 u = *(const uint4*)(Ar + s * 32);
            af[s] = *(short8*)&u;
        }
    }

    #pragma unroll
    for (int t = 0; t < 8; ++t)
        #pragma unroll
        for (int s = 0; s < 4; ++s)
            acc[t] = __builtin_amdgcn_mfma_f32_16x16x32_bf16(af[s], wf[t][s], acc[t], 0, 0, 0);

    // epilogue: C/D layout col = t*16 + c, row = rowbase + q*4 + r
    if (outf) {
        #pragma unroll
        for (int t = 0; t < 8; ++t)
            #pragma unroll
            for (int r = 0; r < 4; ++r) {
                int row = rowbase + q * 4 + r;
                if (row < M)
                    outf[(long)row * DIMC + t * 16 + c] = acc[t][r];
            }
    } else {
        #pragma unroll
        for (int t = 0; t < 8; ++t)
            #pragma unroll
            for (int r = 0; r < 4; ++r) {
                float other = __shfl_xor(acc[t][r], 1);
                int row = rowbase + q * 4 + r;
                if ((lane & 1) == 0 && row < M) {
                    unsigned word = pk2(acc[t][r], other);
                    ((unsigned*)outb)[((long)row * 64 + t * 8 + (c >> 1))
                                      * (long)ostride + ooff] = word;
                }
            }
    }
}

// ---------------- CSR build (multi-kernel, measured fast) ----------------
__global__ void hist_kernel(const int* __restrict__ dst, int* __restrict__ deg, int E) {
    int e = blockIdx.x * blockDim.x + threadIdx.x;
    if (e < E) atomicAdd(&deg[dst[e]], 1);
}

__global__ __launch_bounds__(256) void partial_sums(const int* __restrict__ deg,
                                                    int* __restrict__ partial, int N)
{
    __shared__ int sh[256];
    int t = threadIdx.x;
    int beg = blockIdx.x * 1024 + t * 4;
    int s = 0;
    if (beg + 3 < N) { int4 v = *(const int4*)(deg + beg); s = v.x + v.y + v.z + v.w; }
    else { for (int j = 0; j < 4; ++j) if (beg + j < N) s += deg[beg + j]; }
    sh[t] = s;
    __syncthreads();
    for (int d = 128; d >= 1; d >>= 1) {
        if (t < d) sh[t] += sh[t + d];
        __syncthreads();
    }
    if (t == 0) partial[blockIdx.x] = sh[0];
}

__global__ __launch_bounds__(256) void scan_partials(int* __restrict__ partial, int nb)
{
    __shared__ int sh[256];
    int t = threadIdx.x;
    sh[t] = (t < nb) ? partial[t] : 0;
    __syncthreads();
    for (int d = 1; d < 256; d <<= 1) {
        int v = (t >= d) ? sh[t - d] : 0;
        __syncthreads();
        sh[t] += v;
        __syncthreads();
    }
    if (t < nb) partial[t] = (t == 0) ? 0 : sh[t - 1];
}

__global__ __launch_bounds__(256) void write_offsets(const int* __restrict__ deg,
                                                     const int* __restrict__ partial,
                                                     int* __restrict__ offs,
                                                     int* __restrict__ cursor, int N)
{
    __shared__ int sh[256];
    int t = threadIdx.x;
    int beg = blockIdx.x * 1024 + t * 4;
    int d0 = 0, d1 = 0, d2 = 0, d3 = 0;
    if (beg + 3 < N) { int4 v = *(const int4*)(deg + beg); d0 = v.x; d1 = v.y; d2 = v.z; d3 = v.w; }
    else {
        if (beg < N)     d0 = deg[beg];
        if (beg + 1 < N) d1 = deg[beg + 1];
        if (beg + 2 < N) d2 = deg[beg + 2];
        if (beg + 3 < N) d3 = deg[beg + 3];
    }
    int s = d0 + d1 + d2 + d3;
    sh[t] = s;
    __syncthreads();
    for (int d = 1; d < 256; d <<= 1) {
        int v = (t >= d) ? sh[t - d] : 0;
        __syncthreads();
        sh[t] += v;
        __syncthreads();
    }
    int base = partial[blockIdx.x] + sh[t] - s;
    int o0 = base, o1 = o0 + d0, o2 = o1 + d1, o3 = o2 + d2;
    if (beg < N)     { offs[beg]     = o0; cursor[beg]     = o0; }
    if (beg + 1 < N) { offs[beg + 1] = o1; cursor[beg + 1] = o1; }
    if (beg + 2 < N) { offs[beg + 2] = o2; cursor[beg + 2] = o2; }
    if (beg + 3 < N) { offs[beg + 3] = o3; cursor[beg + 3] = o3; }
}

__global__ void scatter_kernel(const int* __restrict__ src, const int* __restrict__ dst,
                               const int* __restrict__ etype, int* __restrict__ cursor,
                               int2* __restrict__ sedge, int E)
{
    int e = blockIdx.x * blockDim.x + threadIdx.x;
    if (e < E) {
        int d = dst[e];
        int p = atomicAdd(&cursor[d], 1);
        sedge[p] = make_int2(src[e], etype[e]);
    }
}

// ---------------- per-node dual softmax + V aggregation, half-wave edge parallel -----------
// wave = 1 node; half-wave (32 lanes) = 1 edge stream, lane owns 4 dims (uint4 gathers).
// Each half keeps private online-softmax state; merged once via shfl_xor(32).
__global__ __launch_bounds__(256) void node_kernel(
    const float* __restrict__ Qn,
    const uint4* __restrict__ KV4,    // [n*32 + hl]: K pair dims(4hl,4hl+1)=.x, V pair=.y, K(4hl+2,4hl+3)=.z, V=.w
    const uint4* __restrict__ QK4,    // [t*32 + hl]: Qre=.x/.z, Kre=.y/.w
    const int* __restrict__ offs, const int* __restrict__ deg,
    const int2* __restrict__ sedge,
    float* __restrict__ out_sta, uint2* __restrict__ feat_dyn,
    int N, int R)
{
    int n = (blockIdx.x * blockDim.x + threadIdx.x) >> 6;
    int lane = threadIdx.x & 63;
    if (n >= N) return;
    const int hl = lane & 31;   // lane within half
    const int h  = lane >> 5;   // half id

    const float cs = 0.08838834764831845f * 1.4426950408889634f;  // (1/sqrt(128))*log2(e)
    int base = offs[n];
    int dcnt = deg[n];

    float4 qn = ((const float4*)(Qn + (long)n * DIMC))[hl];   // dims 4hl..4hl+3

    // self-loop (half 0 contributes; half 1 starts empty)
    uint4 kvs = KV4[(unsigned)n * 32u + hl];
    uint4 qks = QK4[(unsigned)R * 32u + hl];
    {
        float2 k0 = bf2f2(kvs.x), k1 = bf2f2(kvs.z);
        float2 qr0 = bf2f2(qks.x), qr1 = bf2f2(qks.z);
        float2 kr0 = bf2f2(qks.y), kr1 = bf2f2(qks.w);
        float p = (qn.x + qr0.x) * (k0.x + kr0.x)
                + (qn.y + qr0.y) * (k0.y + kr0.y)
                + (qn.z + qr1.x) * (k1.x + kr1.x)
                + (qn.w + qr1.y) * (k1.y + kr1.y);
        #pragma unroll
        for (int m = 16; m >= 1; m >>= 1) p += __shfl_xor(p, m);
        kvs.x = __float_as_uint(p);   // stash a_self*? no — recompute below
        qks.x = 0;                    // unused after
        // store a_self in p via broadcast; fall through using p
        float a_self = p * cs;
        float2 v0 = bf2f2(kvs.y), v1 = bf2f2(kvs.w);
        // init state
        float m_d, s_d, m_s, s_s; float4 accd, accs;
        if (h == 0) {
            m_d = a_self;  s_d = 1.0f;
            m_s = -a_self; s_s = 1.0f;
            accd = make_float4(v0.x, v0.y, v1.x, v1.y);
            accs = accd;
        } else {
            m_d = -1e30f; s_d = 0.0f;
            m_s = -1e30f; s_s = 0.0f;
            accd = make_float4(0.f, 0.f, 0.f, 0.f);
            accs = accd;
        }

        // edge loop: 4 edges per iteration (2 per half)
        int T = (dcnt + 3) >> 2;
        for (int it = 0; it < T; ++it) {
            int iA = 4 * it + 2 * h, iB = iA + 1;
            bool vA = iA < dcnt, vB = iB < dcnt;
            int2 eA = sedge[vA ? (base + iA) : 0];
            int2 eB = sedge[vB ? (base + iB) : 0];
            uint4 kvA = KV4[(unsigned)eA.x * 32u + hl];
            uint4 kvB = KV4[(unsigned)eB.x * 32u + hl];
            uint4 qkA = QK4[(unsigned)eA.y * 32u + hl];
            uint4 qkB = QK4[(unsigned)eB.y * 32u + hl];

            float2 ka0 = bf2f2(kvA.x), ka1 = bf2f2(kvA.z);
            float2 qa0 = bf2f2(qkA.x), qa1 = bf2f2(qkA.z);
            float2 ra0 = bf2f2(qkA.y), ra1 = bf2f2(qkA.w);
            float pA = (qn.x + qa0.x) * (ka0.x + ra0.x)
                     + (qn.y + qa0.y) * (ka0.y + ra0.y)
                     + (qn.z + qa1.x) * (ka1.x + ra1.x)
                     + (qn.w + qa1.y) * (ka1.y + ra1.y);
            float2 kb0 = bf2f2(kvB.x), kb1 = bf2f2(kvB.z);
            float2 qb0 = bf2f2(qkB.x), qb1 = bf2f2(qkB.z);
            float2 rb0 = bf2f2(qkB.y), rb1 = bf2f2(qkB.w);
            float pB = (qn.x + qb0.x) * (kb0.x + rb0.x)
                     + (qn.y + qb0.y) * (kb0.y + rb0.y)
                     + (qn.z + qb1.x) * (kb1.x + rb1.x)
                     + (qn.w + qb1.y) * (kb1.y + rb1.y);
            #pragma unroll
            for (int m = 16; m >= 1; m >>= 1) {
                pA += __shfl_xor(pA, m);
                pB += __shfl_xor(pB, m);
            }
            float aA = pA * cs, aB = pB * cs;
            float dA = vA ? aA : -1e30f, dB = vB ? aB : -1e30f;     // dyn logits
            float nA = vA ? -aA : -1e30f, nB = vB ? -aB : -1e30f;   // sta logits

            float2 va0 = bf2f2(kvA.y), va1 = bf2f2(kvA.w);
            float2 vb0 = bf2f2(kvB.y), vb1 = bf2f2(kvB.w);

            // dyn
            {
                float mn = fmaxf(m_d, fmaxf(dA, dB));
                float f  = exp2f(m_d - mn);
                float wA = vA ? exp2f(dA - mn) : 0.0f;
                float wB = vB ? exp2f(dB - mn) : 0.0f;
                s_d = fmaf(s_d, f, wA + wB);
                accd.x = fmaf(accd.x, f, fmaf(wA, va0.x, wB * vb0.x));
                accd.y = fmaf(accd.y, f, fmaf(wA, va0.y, wB * vb0.y));
                accd.z = fmaf(accd.z, f, fmaf(wA, va1.x, wB * vb1.x));
                accd.w = fmaf(accd.w, f, fmaf(wA, va1.y, wB * vb1.y));
                m_d = mn;
            }
            // sta
            {
                float mn = fmaxf(m_s, fmaxf(nA, nB));
                float f  = exp2f(m_s - mn);
                float wA = vA ? exp2f(nA - mn) : 0.0f;
                float wB = vB ? exp2f(nB - mn) : 0.0f;
                s_s = fmaf(s_s, f, wA + wB);
                accs.x = fmaf(accs.x, f, fmaf(wA, va0.x, wB * vb0.x));
                accs.y = fmaf(accs.y, f, fmaf(wA, va0.y, wB * vb0.y));
                accs.z = fmaf(accs.z, f, fmaf(wA, va1.x, wB * vb1.x));
                accs.w = fmaf(accs.w, f, fmaf(wA, va1.y, wB * vb1.y));
                m_s = mn;
            }
        }

        // merge halves (symmetric; both halves compute identical results)
        {
            float mo = __shfl_xor(m_d, 32), so = __shfl_xor(s_d, 32);
            float4 ao;
            ao.x = __shfl_xor(accd.x, 32); ao.y = __shfl_xor(accd.y, 32);
            ao.z = __shfl_xor(accd.z, 32); ao.w = __shfl_xor(accd.w, 32);
            float M = fmaxf(m_d, mo);
            float f0 = exp2f(m_d - M), f1 = exp2f(mo - M);
            s_d = fmaf(s_d, f0, so * f1);
            accd.x = fmaf(accd.x, f0, ao.x * f1);
            accd.y = fmaf(accd.y, f0, ao.y * f1);
            accd.z = fmaf(accd.z, f0, ao.z * f1);
            accd.w = fmaf(accd.w, f0, ao.w * f1);
        }
        {
            float mo = __shfl_xor(m_s, 32), so = __shfl_xor(s_s, 32);
            float4 ao;
            ao.x = __shfl_xor(accs.x, 32); ao.y = __shfl_xor(accs.y, 32);
            ao.z = __shfl_xor(accs.z, 32); ao.w = __shfl_xor(accs.w, 32);
            float M = fmaxf(m_s, mo);
            float f0 = exp2f(m_s - M), f1 = exp2f(mo - M);
            s_s = fmaf(s_s, f0, so * f1);
            accs.x = fmaf(accs.x, f0, ao.x * f1);
            accs.y = fmaf(accs.y, f0, ao.y * f1);
            accs.z = fmaf(accs.z, f0, ao.z * f1);
            accs.w = fmaf(accs.w, f0, ao.w * f1);
        }

        if (h == 0) {
            float denom = (float)(dcnt + 1);
            float id_ = 1.0f / (s_d * denom);
            float is_ = 1.0f / (s_s * denom);
            ((float4*)(out_sta + (long)n * DIMC))[hl] =
                make_float4(accs.x * is_, accs.y * is_, accs.z * is_, accs.w * is_);
            feat_dyn[(unsigned)n * 32u + hl] =
                make_uint2(pk2(accd.x * id_, accd.y * id_), pk2(accd.z * id_, accd.w * id_));
        }
    }
}

// ---------------- launch ----------------
extern "C" void kernel_launch(void* const* d_in, const int* in_sizes, int n_in,
                              void* d_out, int out_size, void* d_ws, size_t ws_size,
                              hipStream_t stream)
{
    const float* curr    = (const float*)d_in[0];
    const float* last    = (const float*)d_in[1];
    const float* relemb  = (const float*)d_in[2];
    const float* selfrel = (const float*)d_in[3];
    const float* Wq      = (const float*)d_in[4];
    const float* bq      = (const float*)d_in[5];
    const float* Wk      = (const float*)d_in[6];
    const float* bk      = (const float*)d_in[7];
    const float* Wv      = (const float*)d_in[8];
    const float* bv      = (const float*)d_in[9];
    const float* dynw    = (const float*)d_in[10];
    const int*   eidx    = (const int*)d_in[11];
    const int*   etype   = (const int*)d_in[12];
    float* out = (float*)d_out;

    const int N = in_sizes[0] / DIMC;   // 40000
    const int E = in_sizes[12];         // 400000
    const int R = in_sizes[2] / DIMC;   // 502
    const int* esrc = eidx;
    const int* edst = eidx + E;

    char* wp = (char*)d_ws;
    auto alloc = [&](size_t bytes) { char* r = wp; wp += (bytes + 15) & ~(size_t)15; return r; };
    size_t nd = (size_t)N * DIMC;
    float*          Qn    = (float*)alloc(nd * 4);
    uint4*          KV    = (uint4*)alloc((size_t)N * 32 * 16);
    unsigned short* Fdb   = (unsigned short*)alloc(nd * 2);
    uint4*          QKre  = (uint4*)alloc((size_t)(R + 1) * 32 * 16);
    float*          TypeEmb = (float*)alloc((size_t)(R + 2) * DIMC * 4);
    unsigned short* FW[6];
    for (int m = 0; m < 6; ++m) FW[m] = (unsigned short*)alloc(2048 * 8 * 2);
    int*            deg   = (int*)alloc((size_t)N * 4);
    int*            offs  = (int*)alloc((size_t)N * 4);
    int*            cursor= (int*)alloc((size_t)N * 4);
    int2*           sedge = (int2*)alloc((size_t)E * 8);
    int*            partial = (int*)alloc(256 * 4);

    const int gblk = N / 64;                 // 625
    const int sblk = (N + 1023) / 1024;      // 40

    // 1. fused prep (also zeroes deg)
    PrepArgs pa;
    pa.W[0] = Wq;   pa.W[1] = Wk;   pa.W[2] = Wv;
    pa.W[3] = dynw; pa.W[4] = Wq + (size_t)DIMC * DIMC; pa.W[5] = Wk + (size_t)DIMC * DIMC;
    for (int m = 0; m < 6; ++m) pa.F[m] = FW[m];
    pa.relemb = relemb; pa.selfrel = selfrel; pa.TypeEmb = TypeEmb;
    pa.deg = deg; pa.R = R; pa.N = N;
    int pgrid = 192 + (R + 1) + (N + 63) / 64;
    hipLaunchKernelGGL(prep_all, dim3(pgrid), dim3(64), 0, stream, pa);

    // 2. CSR build (multi-kernel)
    hipLaunchKernelGGL(hist_kernel, dim3((E + 255) / 256), dim3(256), 0, stream, edst, deg, E);
    hipLaunchKernelGGL(partial_sums, dim3(sblk), dim3(256), 0, stream, deg, partial, N);
    hipLaunchKernelGGL(scan_partials, dim3(1), dim3(256), 0, stream, partial, sblk);
    hipLaunchKernelGGL(write_offsets, dim3(sblk), dim3(256), 0, stream,
                       deg, partial, offs, cursor, N);
    hipLaunchKernelGGL(scatter_kernel, dim3((E + 255) / 256), dim3(256), 0, stream,
                       esrc, edst, etype, cursor, sedge, E);

    // 3. all five projections in one MFMA dispatch
    GemmM5 g5;
    for (int s = 0; s < 5; ++s) { g5.Ab[s] = nullptr; g5.outf[s] = nullptr; g5.outb[s] = nullptr; }
    g5.Af[0] = curr;    g5.F[0] = FW[0]; g5.bias[0] = nullptr; g5.outf[0] = Qn;
    g5.ostride[0] = 1;  g5.ooff[0] = 0;  g5.M[0] = N;
    g5.Af[1] = last;    g5.F[1] = FW[1]; g5.bias[1] = nullptr; g5.outb[1] = (unsigned short*)KV;
    g5.ostride[1] = 2;  g5.ooff[1] = 0;  g5.M[1] = N;
    g5.Af[2] = last;    g5.F[2] = FW[2]; g5.bias[2] = bv;      g5.outb[2] = (unsigned short*)KV;
    g5.ostride[2] = 2;  g5.ooff[2] = 1;  g5.M[2] = N;
    g5.Af[3] = TypeEmb; g5.F[3] = FW[4]; g5.bias[3] = bq;      g5.outb[3] = (unsigned short*)QKre;
    g5.ostride[3] = 2;  g5.ooff[3] = 0;  g5.M[3] = R + 1;
    g5.Af[4] = TypeEmb; g5.F[4] = FW[5]; g5.bias[4] = bk;      g5.outb[4] = (unsigned short*)QKre;
    g5.ostride[4] = 2;  g5.ooff[4] = 1;  g5.M[4] = R + 1;
    hipLaunchKernelGGL(gemm_mfma, dim3(gblk, 5), dim3(256), 0, stream, g5);

    // 4. node aggregation
    hipLaunchKernelGGL(node_kernel, dim3((N + 3) / 4), dim3(256), 0, stream,
                       Qn, KV, QKre, offs, deg, sedge, out, (uint2*)Fdb, N, R);

    // 5. final GEMM: feat_dyn @ dyn_weight
    GemmM5 gf;
    for (int s = 0; s < 5; ++s) { gf.Af[s] = nullptr; gf.Ab[s] = nullptr; gf.outf[s] = nullptr; gf.outb[s] = nullptr; gf.M[s] = 0; }
    gf.Ab[0] = Fdb; gf.F[0] = FW[3]; gf.bias[0] = nullptr; gf.outf[0] = out + nd;
    gf.ostride[0] = 1; gf.ooff[0] = 0; gf.M[0] = N;
    hipLaunchKernelGGL(gemm_mfma, dim3(gblk, 1), dim3(256), 0, stream, gf);
}